// Round 14
// baseline (109.325 us; speedup 1.0000x reference)
//
#include <hip/hip_runtime.h>

typedef __attribute__((ext_vector_type(8))) short bf16x8;
typedef __attribute__((ext_vector_type(4))) float f32x4;
typedef __attribute__((ext_vector_type(4))) unsigned short us4;
typedef __attribute__((ext_vector_type(8))) unsigned short us8;

#define E_DIM 100
#define L_SEQ 20
#define NV    30000
#define MROWS 2000
#define KP    128
#define KW    112
#define WSTR  53        // W1/W2 LDS row stride in float4
#define GXL_S 404       // gxl row stride (floats): 404%32=20 -> spread banks

__device__ inline unsigned short f2bf(float f){
  unsigned int u = __float_as_uint(f);
  return (unsigned short)((u + 0x7fffu + ((u>>16)&1u)) >> 16);
}
__device__ inline float dot4(float4 a, float4 b){
  return a.x*b.x + a.y*b.y + a.z*b.z + a.w*b.w;
}
__device__ inline void store4bf(unsigned short* dst, float4 x){
  us4 p = { f2bf(x.x), f2bf(x.y), f2bf(x.z), f2bf(x.w) };
  *(us4*)dst = p;
}
__device__ inline float fsig(float x){
  float t = __builtin_amdgcn_exp2f(x * -1.44269504f);
  return __builtin_amdgcn_rcpf(1.f + t);
}
__device__ inline float ftanh(float x){
  float cx = fminf(fmaxf(x, -15.f), 15.f);
  float t = __builtin_amdgcn_exp2f(cx * 2.88539008f);
  return (t - 1.f) * __builtin_amdgcn_rcpf(t + 1.f);
}

// ---------------- G: ib conversion + whhb only ----------------
#define GC1 962560
#define GC2 973760
__global__ void gather_kernel(const float* __restrict__ item, const float* __restrict__ W_hh,
    unsigned short* __restrict__ ib, unsigned short* __restrict__ whhb){
  int id = blockIdx.x*256 + threadIdx.x;
  if (id < GC1){
    int v = id >> 5, k4 = (id & 31) << 2;
    float4 x = {0.f,0.f,0.f,0.f};
    if (v < NV && k4 < 100) x = *(const float4*)(item + (size_t)v*E_DIM + k4);
    store4bf(ib + (size_t)v*KP + k4, x);
  } else if (id < GC2){
    int idx = id - GC1;
    int j = idx / 28, k4 = (idx - j*28) << 2;
    float4 x = {0.f,0.f,0.f,0.f};
    if (k4 < 100) x = *(const float4*)(W_hh + (size_t)j*E_DIM + k4);
    store4bf(whhb + (size_t)j*KW + k4, x);
  }
}

// ---------------- PREP: everything pre-GEMM, one block/session ----------------
// LDS arena (bytes), phase-aliased:
//   0      wihb_swz bf16[400][128] (102400)  -> later Wsh f32 W1/W2 (84800)
//   102400 gxl f32[25][404] (40400)          -> later ns/wsc/ctx/h04 (F/G)
//   142800 xsb_swz bf16[25..31][128] (8000 region) -> later hu f32[20][100]
//   150800 hsb(256) 151056 gsh(1600) 152656 biasv(1600)
//   154256 stcat f32[5][200](4000) 158256 ls2l f32[5][100](2000)  => 160256 B
__global__ __launch_bounds__(512,1) void prep_kernel(
    const int* __restrict__ seq, const int* __restrict__ ss2,
    const int* __restrict__ sn2, const int* __restrict__ mask,
    const float* __restrict__ user, const float* __restrict__ item,
    const float* __restrict__ W_ih, const float* __restrict__ b_ih,
    const float* __restrict__ b_hh, const float* __restrict__ W1,
    const float* __restrict__ W2, const float* __restrict__ Wg0,
    const unsigned short* __restrict__ whhb, unsigned short* __restrict__ srb){
  __shared__ float4 arena4[10016];            // 160,256 B
  char* AR = (char*)arena4;
  int b = blockIdx.x, tid = threadIdx.x;
  int wave = tid >> 6, lane = tid & 63;
  int lrow = lane & 15, lq = lane >> 4;

  float4* Wsh   = (float4*)AR;                       // aliases wihb after phase B
  float*  gxl   = (float*)(AR + 102400);
  float*  nsf   = (float*)(AR + 102400);             // [6][100] (F)
  float*  wsc   = (float*)(AR + 102400 + 2400);      // [8] (F)
  float*  ctx   = (float*)(AR + 102432 + 2400);      // [100] (F)  (102400+2432)
  float*  h04   = (float*)(AR + 105232);             // [100] f32 (F/G)
  float*  hu    = (float*)(AR + 142800);             // [20][100] (aliases xsb)
  unsigned short* hsb = (unsigned short*)(AR + 150800);
  float*  gsh   = (float*)(AR + 151056);
  float*  biasv = (float*)(AR + 152656);
  float*  stcat = (float*)(AR + 154256);             // [5][200]
  float*  ls2l  = (float*)(AR + 158256);             // [5][100]

  // ---- phase A: stage wihb (W_ih->bf16 swizzled), xsb (25 x-rows), biasv, hsb ----
  for (int u = tid; u < 6400; u += 512){              // wihb: 400 rows x 16 chunks
    int row = u >> 4, c16 = u & 15, k0 = c16 << 3;
    const float* src = W_ih + (size_t)row*E_DIM + k0;
    us8 pk;
    if (k0 + 8 <= 100){
      float4 a = *(const float4*)src, c2 = *(const float4*)(src+4);
      pk = (us8){f2bf(a.x),f2bf(a.y),f2bf(a.z),f2bf(a.w),f2bf(c2.x),f2bf(c2.y),f2bf(c2.z),f2bf(c2.w)};
    } else {
#pragma unroll
      for (int q=0;q<8;q++) pk[q] = (k0+q < 100) ? f2bf(src[q]) : (unsigned short)0;
    }
    *(us8*)(AR + ((row*256 + (c16<<4)) ^ ((row&7)<<4))) = pk;
  }
  for (int u = tid; u < 400; u += 512){               // xsb: 25 rows x 16 chunks
    int row = u >> 4, c16 = u & 15, k0 = c16 << 3;
    int sidx = (row < L_SEQ) ? seq[b*L_SEQ + row] : ss2[(b*5 + row - L_SEQ)*L_SEQ];
    const float* src = item + (size_t)sidx*E_DIM + k0;
    us8 pk;
    if (k0 + 8 <= 100){
      float4 a = *(const float4*)src, c2 = *(const float4*)(src+4);
      pk = (us8){f2bf(a.x),f2bf(a.y),f2bf(a.z),f2bf(a.w),f2bf(c2.x),f2bf(c2.y),f2bf(c2.z),f2bf(c2.w)};
    } else {
#pragma unroll
      for (int q=0;q<8;q++) pk[q] = (k0+q < 100) ? f2bf(src[q]) : (unsigned short)0;
    }
    *(us8*)(AR + 142800 + ((row*256 + (c16<<4)) ^ ((row&7)<<4))) = pk;
  }
  if (tid < 400) biasv[tid] = b_ih[tid] + b_hh[tid];
  if (tid < 128) hsb[tid] = 0;
  __syncthreads();

  // ---- phase B: gxl[xrow][gate] = x . W_ih^T  (MFMA; arg1=W rows -> gate on row axis,
  //      arg2=x rows -> xrow on col axis; verified operand convention) ----
  {
    bf16x8 xf0[4], xf1[4];
#pragma unroll
    for (int ks=0; ks<4; ks++){
      int koff = (ks*32 + lq*8) * 2;
      xf0[ks] = *(const bf16x8*)(AR + 142800 + ((lrow*256 + koff) ^ ((lrow&7)<<4)));
      int r1 = 16 + lrow;
      xf1[ks] = *(const bf16x8*)(AR + 142800 + ((r1*256 + koff) ^ ((r1&7)<<4)));
    }
#pragma unroll
    for (int i=0;i<4;i++){
      int nt = wave + 8*i;
      if (nt < 25){
        f32x4 g0 = (f32x4){0.f,0.f,0.f,0.f};
        f32x4 g1 = (f32x4){0.f,0.f,0.f,0.f};
#pragma unroll
        for (int ks=0; ks<4; ks++){
          int row = nt*16 + lrow;
          bf16x8 wfr = *(const bf16x8*)(AR + ((row*256 + (ks*32 + lq*8)*2) ^ ((row&7)<<4)));
          g0 = __builtin_amdgcn_mfma_f32_16x16x32_bf16(wfr, xf0[ks], g0, 0, 0, 0);
          g1 = __builtin_amdgcn_mfma_f32_16x16x32_bf16(wfr, xf1[ks], g1, 0, 0, 0);
        }
        *(f32x4*)(&gxl[lrow*GXL_S + nt*16 + lq*4]) = g0;
        if (16 + lrow < 25)
          *(f32x4*)(&gxl[(16+lrow)*GXL_S + nt*16 + lq*4]) = g1;
      }
    }
  }
  __syncthreads();   // gxl ready; wihb region dead -> Wsh restage allowed

  // stage W1 -> Wsh (latency hides under recurrence)
  {
    const float4* w1g = (const float4*)W1;
    for (int u = tid; u < 5000; u += 512){
      int r = u / 50, cc = u - r*50;
      Wsh[r*WSTR + cc] = w1g[u];
    }
  }

  // W_hh fragments pinned (as R10)
  bf16x8 wf[4][4];
#pragma unroll
  for (int i=0;i<4;i++){
    int nt = wave + 8*i;
#pragma unroll
    for (int ks=0; ks<4; ks++){
      bf16x8 z = {0,0,0,0,0,0,0,0};
      int k = ks*32 + lq*8;
      if (nt < 25 && k < KW)
        z = *(const bf16x8*)(whhb + (size_t)(nt*16 + lrow)*KW + k);
      wf[i][ks] = z;
    }
  }
  float c = 0.f;
  __syncthreads();

  // ---- phase D: recurrence, 20 steps (R10 structure; + gxl + biasv) ----
  for (int tt=0; tt<L_SEQ; tt++){
    bf16x8 hf[4];
#pragma unroll
    for (int ks=0; ks<4; ks++)
      hf[ks] = *(const bf16x8*)((char*)hsb + ks*64 + lq*16);
#pragma unroll
    for (int i=0;i<4;i++){
      int nt = wave + 8*i;
      if (nt < 25){
        f32x4 acc = (f32x4){0.f,0.f,0.f,0.f};
#pragma unroll
        for (int ks=0; ks<4; ks++)
          acc = __builtin_amdgcn_mfma_f32_16x16x32_bf16(wf[i][ks], hf[ks], acc, 0, 0, 0);
        if (lrow == 0) *(f32x4*)(&gsh[nt*16 + lq*4]) = acc;
      }
    }
    __syncthreads();
    if (tid < 100){
      const float* gx_t = &gxl[tt*GXL_S];
      float g0 = gsh[tid      ] + gx_t[tid      ] + biasv[tid      ];
      float g1 = gsh[tid + 100] + gx_t[tid + 100] + biasv[tid + 100];
      float g2 = gsh[tid + 200] + gx_t[tid + 200] + biasv[tid + 200];
      float g3 = gsh[tid + 300] + gx_t[tid + 300] + biasv[tid + 300];
      float ig = fsig(g0), fg = fsig(g1);
      float gg = ftanh(g2), og = fsig(g3);
      c = fg*c + ig*gg;
      float h = og * ftanh(c);
      hsb[tid] = f2bf(h);
      hu[tt*100 + tid] = h;
    }
    __syncthreads();
  }

  // ---- phase E: stageb (support x-gates from gxl rows 20..24; W1 from LDS) ----
  int s = tid / 100, j2 = tid - s*100;
  if (tid < 500){
    int n = b*5 + s;
    stcat[s*200 + j2] = user[(size_t)sn2[n]*E_DIM + j2];
    const float* gr = &gxl[(L_SEQ + s)*GXL_S];
    float c0  = fsig(gr[j2] + biasv[j2]) * ftanh(gr[200+j2] + biasv[200+j2]);
    stcat[s*200 + 100 + j2] = fsig(gr[300+j2] + biasv[300+j2]) * ftanh(c0);
  }
  __syncthreads();      // gxl reads done (except none later); stcat ready
  if (tid < 500){
    float acc = 0.f;
    const float4* w1row = Wsh + j2*WSTR;
    const float4* cc4 = (const float4*)(stcat + s*200);
#pragma unroll
    for (int k=0;k<50;k++) acc += dot4(w1row[k], cc4[k]);
    ls2l[s*100 + j2] = fmaxf(acc, 0.f);
  }
  __syncthreads();      // all W1 reads done

  // restage Wsh with W2 (hidden under GAT)
  {
    const float4* w2g = (const float4*)W2;
    for (int u = tid; u < 5000; u += 512){
      int r = u / 50, cc = u - r*50;
      Wsh[r*WSTR + cc] = w2g[u];
    }
  }

  // ---- phase F: GAT -> h04 (ns/wsc/ctx/h04 alias gxl region, dead now) ----
  if (tid < 100) nsf[5*100 + tid] = hu[tid];
  if (tid < 500) nsf[s*100 + j2] = ls2l[s*100 + j2];
  __syncthreads();
  if (wave < 6){
    float p = 0.f;
    if (lane < 100) p = nsf[5*100 + lane] * nsf[wave*100 + lane];
    if (lane + 64 < 100) p += nsf[5*100 + lane+64] * nsf[wave*100 + lane+64];
#pragma unroll
    for (int off=32; off>0; off>>=1) p += __shfl_xor(p, off);
    if (lane == 0) wsc[wave] = p;
  }
  __syncthreads();
  if (tid == 0){
    float m=wsc[0]; for (int k=1;k<6;k++) m=fmaxf(m,wsc[k]);
    float sum=0.f;
    for (int k=0;k<6;k++){ float e_=__builtin_amdgcn_exp2f((wsc[k]-m)*1.44269504f); wsc[k]=e_; sum+=e_; }
    float inv=1.f/sum;
    for (int k=0;k<6;k++) wsc[k]*=inv;
  }
  __syncthreads();
  if (tid < 100){ float cx=0.f; for (int k=0;k<6;k++) cx += wsc[k]*nsf[k*100 + tid]; ctx[tid]=cx; }
  __syncthreads();
  if (tid < 100){
    float acc=0.f;
    for (int e=0;e<100;e++) acc += ctx[e]*Wg0[e*E_DIM + tid];
    h04[tid] = fmaxf(acc, 0.f);
  }
  __syncthreads();      // h04 ready AND W2 restage visible

  // ---- phase G: sr rows (mask folded; W2 from LDS), bf16, K-pad ----
  {
    const float4* hu44 = (const float4*)hu;
    const float4* h044 = (const float4*)h04;
    int mi4 = tid >> 7;
    int jj  = tid & 127;
#pragma unroll
    for (int r=0;r<5;r++){
      int mi = r*4 + mi4;
      int m  = b*L_SEQ + mi;
      unsigned short val = 0;
      if (jj < 100){
        float acc = 0.f;
        const float4* w2row = Wsh + jj*WSTR;
#pragma unroll
        for (int k=0;k<25;k++) acc += dot4(w2row[k],    hu44[mi*25 + k]);
#pragma unroll
        for (int k=0;k<25;k++) acc += dot4(w2row[25+k], h044[k]);
        acc *= (float)mask[m];
        val = f2bf(acc);
      }
      srb[(size_t)m*KP + jj] = val;
    }
    if (b < 48 && tid < 128) srb[(size_t)(MROWS + b)*KP + tid] = 0;
  }
}

// ---------------- E: logits = srb @ ib^T (bf16 MFMA, f32 acc) ----------------
__global__ __launch_bounds__(256) void gemm_kernel(
    const unsigned short* __restrict__ srb, const unsigned short* __restrict__ ib,
    float* __restrict__ out){
  __shared__ unsigned short As[128*KP];
  __shared__ unsigned short Bs[128*KP];
  int orig = blockIdx.x;               // 0..3759 = 8 XCD * 470
  int xcd  = orig & 7;
  int p    = orig >> 3;
  int tile_n = p >> 1;
  int tile_m = (xcd << 1) | (p & 1);
  int tid = threadIdx.x;
  const float4* Ag = (const float4*)(srb + (size_t)tile_m*128*KP);
  const float4* Bg = (const float4*)(ib  + (size_t)tile_n*128*KP);
  float4* As4=(float4*)As; float4* Bs4=(float4*)Bs;
#pragma unroll
  for (int i=0;i<8;i++){
    int chunk = i*256 + tid;
    int row = chunk >> 4;
    int cb  = (chunk & 15) << 4;
    int sw  = cb ^ ((row & 7) << 4);
    int di  = row*16 + (sw >> 4);
    As4[di] = Ag[chunk];
    Bs4[di] = Bg[chunk];
  }
  __syncthreads();
  int wave = tid >> 6, lane = tid & 63;
  int wm = (wave >> 1) << 6, wn = (wave & 1) << 6;
  int lrow = lane & 15, lq = lane >> 4;
  f32x4 acc[4][4];
#pragma unroll
  for (int i=0;i<4;i++)
#pragma unroll
    for (int jj=0;jj<4;jj++) acc[i][jj] = (f32x4){0.f,0.f,0.f,0.f};
#pragma unroll
  for (int kk=0;kk<4;kk++){
    int koffb = (kk*32 + lq*8) * 2;
    bf16x8 a[4], bfr[4];
#pragma unroll
    for (int i=0;i<4;i++){
      int row = wm + i*16 + lrow;
      int boff = koffb ^ ((row & 7) << 4);
      a[i] = *(const bf16x8*)(As + row*KP + (boff >> 1));
    }
#pragma unroll
    for (int jj=0;jj<4;jj++){
      int row = wn + jj*16 + lrow;
      int boff = koffb ^ ((row & 7) << 4);
      bfr[jj] = *(const bf16x8*)(Bs + row*KP + (boff >> 1));
    }
#pragma unroll
    for (int i=0;i<4;i++)
#pragma unroll
      for (int jj=0;jj<4;jj++)
        acc[i][jj] = __builtin_amdgcn_mfma_f32_16x16x32_bf16(bfr[jj], a[i], acc[i][jj], 0, 0, 0);
  }
  int v0 = tile_n*128 + wn + lq*4;
  int m0 = tile_m*128 + wm + lrow;
#pragma unroll
  for (int i=0;i<4;i++){
    int m = m0 + i*16;
    if (m < MROWS){
#pragma unroll
      for (int jj=0;jj<4;jj++){
        int v = v0 + jj*16;
        if (v < NV)
          *(float4*)(out + (size_t)m*NV + v) = (float4){acc[i][jj][0], acc[i][jj][1], acc[i][jj][2], acc[i][jj][3]};
      }
    }
  }
}

extern "C" void kernel_launch(void* const* d_in, const int* in_sizes, int n_in,
                              void* d_out, int out_size, void* d_ws, size_t ws_size,
                              hipStream_t stream) {
  const int*   seq  = (const int*)d_in[0];
  const int*   sn2  = (const int*)d_in[2];
  const int*   ss2  = (const int*)d_in[4];
  const int*   mask = (const int*)d_in[5];
  const float* user = (const float*)d_in[6];
  const float* item = (const float*)d_in[7];
  const float* W_ih = (const float*)d_in[8];
  const float* W_hh = (const float*)d_in[9];
  const float* b_ih = (const float*)d_in[10];
  const float* b_hh = (const float*)d_in[11];
  const float* W1   = (const float*)d_in[12];
  const float* W2   = (const float*)d_in[13];
  const float* Wg0  = (const float*)d_in[14];
  float* out = (float*)d_out;
  char* ws = (char*)d_ws;

  unsigned short* ib   = (unsigned short*)(ws);             // 7,700,480 B
  unsigned short* srb  = (unsigned short*)(ws + 7700480);   //   524,288 B
  unsigned short* whhb = (unsigned short*)(ws + 8224768);   //    89,600 B

  gather_kernel<<<dim3(3804), dim3(256), 0, stream>>>(item, W_hh, ib, whhb);
  prep_kernel<<<dim3(100), dim3(512), 0, stream>>>(
      seq, ss2, sn2, mask, user, item, W_ih, b_ih, b_hh, W1, W2, Wg0, whhb, srb);
  gemm_kernel<<<dim3(3760), dim3(256), 0, stream>>>(srb, ib, out);
}